// Round 1
// baseline (673.733 us; speedup 1.0000x reference)
//
#include <hip/hip_runtime.h>

#define N_NODES 100000
#define N_EDGES 1600000
#define IN_F    128
#define HEADS   4
#define OUT_F   16
#define HF      64          // HEADS*OUT_F
#define NEG_SLOPE 0.2f

// ---------------- k0: init out with bias, zero denom ----------------
__global__ __launch_bounds__(256) void k0_init(const float* __restrict__ bias,
                                               float* __restrict__ out,
                                               float* __restrict__ denom) {
    int idx = blockIdx.x * 256 + threadIdx.x;
    if (idx < N_NODES * HF)    out[idx]   = bias[idx & 63];
    if (idx < N_NODES * HEADS) denom[idx] = 0.f;
}

// ---------------- k1: z = feats @ W^T, el/er head logits ----------------
// block = 256 threads = 4 waves; each wave does 8 nodes; 32 nodes/block.
// W^T staged in LDS with stride 65 (65 % 32 == 1 -> 2-way bank alias, free).
__global__ __launch_bounds__(256) void k1_proj(const float* __restrict__ feats,
                                               const float* __restrict__ W,
                                               const float* __restrict__ attn_l,
                                               const float* __restrict__ attn_r,
                                               float* __restrict__ z,
                                               float* __restrict__ el,
                                               float* __restrict__ er) {
    __shared__ float Wt[IN_F * 65];   // Wt[k*65 + c] = W[c*IN_F + k]
    const int tid = threadIdx.x;
    for (int i = tid; i < HF * IN_F; i += 256) {
        int c = i >> 7, k = i & 127;
        Wt[k * 65 + c] = W[i];
    }
    __syncthreads();

    const int wave = tid >> 6, lane = tid & 63;
    const int h = lane >> 4;
    const float al = attn_l[lane];    // flat [h*16+f] == lane
    const float ar = attn_r[lane];

    for (int j = 0; j < 8; ++j) {
        const int node = blockIdx.x * 32 + wave * 8 + j;
        const float4* frow = (const float4*)(feats + (size_t)node * IN_F);
        float acc = 0.f;
        #pragma unroll
        for (int k4 = 0; k4 < IN_F / 4; ++k4) {
            float4 f = frow[k4];      // wave-uniform address -> broadcast
            int k = k4 * 4;
            acc += f.x * Wt[(k + 0) * 65 + lane];
            acc += f.y * Wt[(k + 1) * 65 + lane];
            acc += f.z * Wt[(k + 2) * 65 + lane];
            acc += f.w * Wt[(k + 3) * 65 + lane];
        }
        z[(size_t)node * HF + lane] = acc;

        // head-wise reduce over the 16 lanes of each head
        float vl = acc * al, vr = acc * ar;
        #pragma unroll
        for (int off = 8; off >= 1; off >>= 1) {
            vl += __shfl_xor(vl, off, 16);
            vr += __shfl_xor(vr, off, 16);
        }
        if ((lane & 15) == 0) {
            el[node * HEADS + h] = vl;
            er[node * HEADS + h] = vr;
        }
    }
}

__device__ __forceinline__ float edge_exp(const float* el, const float* er,
                                          int s, int d, int h) {
    float x = el[s * HEADS + h] + er[d * HEADS + h];
    x = x > 0.f ? x : NEG_SLOPE * x;
    return __expf(x);   // no max-shift: alpha is shift-invariant, logits O(1)
}

// ---------------- k2: denom[d,h] = sum_e exp(e) ----------------
__global__ __launch_bounds__(256) void k2_denom(const int* __restrict__ src,
                                                const int* __restrict__ dst,
                                                const float* __restrict__ el,
                                                const float* __restrict__ er,
                                                float* __restrict__ denom) {
    int idx = blockIdx.x * 256 + threadIdx.x;   // exact: E*4 threads
    int e = idx >> 2, h = idx & 3;
    int s = src[e], d = dst[e];
    unsafeAtomicAdd(&denom[d * HEADS + h], edge_exp(el, er, s, d, h));
}

// ---------------- k3: out[d] += alpha * z[s], one wave per edge ----------------
__global__ __launch_bounds__(256) void k3_aggr(const int* __restrict__ src,
                                               const int* __restrict__ dst,
                                               const float* __restrict__ el,
                                               const float* __restrict__ er,
                                               const float* __restrict__ denom,
                                               const float* __restrict__ z,
                                               float* __restrict__ out) {
    int edge = blockIdx.x * 4 + (threadIdx.x >> 6);  // exact: E/4 blocks
    int c = threadIdx.x & 63, h = c >> 4;
    int s = src[edge], d = dst[edge];
    float alpha = edge_exp(el, er, s, d, h) / denom[d * HEADS + h];
    unsafeAtomicAdd(&out[d * HF + c], z[(size_t)s * HF + c] * alpha);
}

extern "C" void kernel_launch(void* const* d_in, const int* in_sizes, int n_in,
                              void* d_out, int out_size, void* d_ws, size_t ws_size,
                              hipStream_t stream) {
    const float* feats  = (const float*)d_in[0];
    const float* W      = (const float*)d_in[1];
    const float* attn_l = (const float*)d_in[2];
    const float* attn_r = (const float*)d_in[3];
    const float* bias   = (const float*)d_in[4];
    const int*   src    = (const int*)d_in[5];
    const int*   dst    = (const int*)d_in[6];
    float* out = (float*)d_out;

    float* ws    = (float*)d_ws;
    float* z     = ws;                                   // N*64
    float* el    = z  + (size_t)N_NODES * HF;            // N*4
    float* er    = el + N_NODES * HEADS;                 // N*4
    float* denom = er + N_NODES * HEADS;                 // N*4

    k0_init <<<(N_NODES * HF + 255) / 256, 256, 0, stream>>>(bias, out, denom);
    k1_proj <<<N_NODES / 32,              256, 0, stream>>>(feats, W, attn_l, attn_r, z, el, er);
    k2_denom<<<(N_EDGES * HEADS) / 256,   256, 0, stream>>>(src, dst, el, er, denom);
    k3_aggr <<<N_EDGES / 4,               256, 0, stream>>>(src, dst, el, er, denom, z, out);
}

// Round 2
// 488.015 us; speedup vs baseline: 1.3806x; 1.3806x over previous
//
#include <hip/hip_runtime.h>

#define N_NODES 100000
#define N_EDGES 1600000
#define IN_F    128
#define HEADS   4
#define OUT_F   16
#define HF      64
#define NEG_SLOPE 0.2f
#define NB_SCAN 391        // ceil(N_NODES/256)

// ---------------- zero the histogram ----------------
__global__ __launch_bounds__(256) void k_zero(int* __restrict__ cnt) {
    int i = blockIdx.x * 256 + threadIdx.x;
    if (i < N_NODES) cnt[i] = 0;
}

// ---------------- k1: z = feats @ W^T, el/er head logits ----------------
__global__ __launch_bounds__(256) void k1_proj(const float* __restrict__ feats,
                                               const float* __restrict__ W,
                                               const float* __restrict__ attn_l,
                                               const float* __restrict__ attn_r,
                                               float* __restrict__ z,
                                               float* __restrict__ el,
                                               float* __restrict__ er) {
    __shared__ float Wt[IN_F * 65];   // Wt[k*65 + c] = W[c*IN_F + k]
    const int tid = threadIdx.x;
    for (int i = tid; i < HF * IN_F; i += 256) {
        int c = i >> 7, k = i & 127;
        Wt[k * 65 + c] = W[i];
    }
    __syncthreads();

    const int wave = tid >> 6, lane = tid & 63;
    const int h = lane >> 4;
    const float al = attn_l[lane];
    const float ar = attn_r[lane];

    for (int j = 0; j < 8; ++j) {
        const int node = blockIdx.x * 32 + wave * 8 + j;
        const float4* frow = (const float4*)(feats + (size_t)node * IN_F);
        float acc = 0.f;
        #pragma unroll
        for (int k4 = 0; k4 < IN_F / 4; ++k4) {
            float4 f = frow[k4];
            int k = k4 * 4;
            acc += f.x * Wt[(k + 0) * 65 + lane];
            acc += f.y * Wt[(k + 1) * 65 + lane];
            acc += f.z * Wt[(k + 2) * 65 + lane];
            acc += f.w * Wt[(k + 3) * 65 + lane];
        }
        z[(size_t)node * HF + lane] = acc;

        float vl = acc * al, vr = acc * ar;
        #pragma unroll
        for (int off = 8; off >= 1; off >>= 1) {
            vl += __shfl_xor(vl, off, 16);
            vr += __shfl_xor(vr, off, 16);
        }
        if ((lane & 15) == 0) {
            el[node * HEADS + h] = vl;
            er[node * HEADS + h] = vr;
        }
    }
}

// ---------------- counting sort by dst ----------------
__global__ __launch_bounds__(256) void k_hist(const int* __restrict__ dst,
                                              int* __restrict__ cnt) {
    int e = blockIdx.x * 256 + threadIdx.x;   // exact grid
    atomicAdd(&cnt[dst[e]], 1);
}

__global__ __launch_bounds__(256) void k_scan1(const int* __restrict__ cnt,
                                               int* __restrict__ loc,
                                               int* __restrict__ bsum) {
    __shared__ int s[256];
    int t = threadIdx.x, i = blockIdx.x * 256 + t;
    int v = (i < N_NODES) ? cnt[i] : 0;
    s[t] = v; __syncthreads();
    for (int o = 1; o < 256; o <<= 1) {
        int x = (t >= o) ? s[t - o] : 0;
        __syncthreads();
        s[t] += x;
        __syncthreads();
    }
    if (i < N_NODES) loc[i] = s[t] - v;        // exclusive within block
    if (t == 255) bsum[blockIdx.x] = s[255];
}

__global__ __launch_bounds__(512) void k_scan2(const int* __restrict__ bsum,
                                               int* __restrict__ bsumx) {
    __shared__ int s[512];
    int t = threadIdx.x;
    int v = (t < NB_SCAN) ? bsum[t] : 0;
    s[t] = v; __syncthreads();
    for (int o = 1; o < 512; o <<= 1) {
        int x = (t >= o) ? s[t - o] : 0;
        __syncthreads();
        s[t] += x;
        __syncthreads();
    }
    bsumx[t] = s[t] - v;                       // exclusive
}

__global__ __launch_bounds__(256) void k_scan3(const int* __restrict__ loc,
                                               const int* __restrict__ bsumx,
                                               int* __restrict__ off,
                                               int* __restrict__ cursor) {
    int i = blockIdx.x * 256 + threadIdx.x;
    if (i < N_NODES) {
        int o = loc[i] + bsumx[blockIdx.x];
        off[i] = o;
        cursor[i] = o;
    }
    if (i == 0) off[N_NODES] = N_EDGES;
}

__global__ __launch_bounds__(256) void k_scatter(const int* __restrict__ src,
                                                 const int* __restrict__ dst,
                                                 int* __restrict__ cursor,
                                                 int* __restrict__ ssrc) {
    int e = blockIdx.x * 256 + threadIdx.x;   // exact grid
    int d = dst[e];
    int pos = atomicAdd(&cursor[d], 1);
    ssrc[pos] = src[e];
}

// ---------------- fused softmax + aggregation: one wave per node ----------------
// lane = j*16 + q : j = edge slot (wave covers 4 edges/iter), q = channel quad.
__global__ __launch_bounds__(256) void k3_fused(const int* __restrict__ ssrc,
                                                const int* __restrict__ off,
                                                const float* __restrict__ el,
                                                const float* __restrict__ er,
                                                const float* __restrict__ z,
                                                const float* __restrict__ bias,
                                                float* __restrict__ out) {
    const int node = blockIdx.x * 4 + (threadIdx.x >> 6);   // exact grid
    const int lane = threadIdx.x & 63;
    const int j = lane >> 4;        // 0..3
    const int q = lane & 15;        // channel quad -> channels q*4..q*4+3
    const int h = q >> 2;           // head
    const int lo = off[node], hi = off[node + 1];
    const float er_d = er[node * HEADS + h];

    float4 acc = make_float4(0.f, 0.f, 0.f, 0.f);
    float den = 0.f;

    for (int i = lo + j; i < hi; i += 4) {
        int s = ssrc[i];
        float x = el[s * HEADS + h] + er_d;
        x = x > 0.f ? x : NEG_SLOPE * x;
        float ex = __expf(x);
        den += ex;
        float4 zv = *(const float4*)(z + (size_t)s * HF + q * 4);
        acc.x += ex * zv.x; acc.y += ex * zv.y;
        acc.z += ex * zv.z; acc.w += ex * zv.w;
    }

    // reduce across the 4 edge slots (lane bits 4,5)
    #pragma unroll
    for (int m = 16; m <= 32; m <<= 1) {
        acc.x += __shfl_xor(acc.x, m);
        acc.y += __shfl_xor(acc.y, m);
        acc.z += __shfl_xor(acc.z, m);
        acc.w += __shfl_xor(acc.w, m);
        den   += __shfl_xor(den,   m);
    }

    if (j == 0) {
        float4 b = *(const float4*)(bias + q * 4);
        float4 o;
        if (den > 0.f) {
            float inv = 1.f / den;
            o.x = acc.x * inv + b.x; o.y = acc.y * inv + b.y;
            o.z = acc.z * inv + b.z; o.w = acc.w * inv + b.w;
        } else {
            o = b;                   // node with no incoming edges
        }
        *(float4*)(out + (size_t)node * HF + q * 4) = o;
    }
}

extern "C" void kernel_launch(void* const* d_in, const int* in_sizes, int n_in,
                              void* d_out, int out_size, void* d_ws, size_t ws_size,
                              hipStream_t stream) {
    const float* feats  = (const float*)d_in[0];
    const float* W      = (const float*)d_in[1];
    const float* attn_l = (const float*)d_in[2];
    const float* attn_r = (const float*)d_in[3];
    const float* bias   = (const float*)d_in[4];
    const int*   src    = (const int*)d_in[5];
    const int*   dst    = (const int*)d_in[6];
    float* out = (float*)d_out;

    char* ws = (char*)d_ws;
    float* z      = (float*)ws;                       ws += (size_t)N_NODES * HF * 4;
    float* el     = (float*)ws;                       ws += N_NODES * HEADS * 4;
    float* er     = (float*)ws;                       ws += N_NODES * HEADS * 4;
    int*   cnt    = (int*)ws;                         ws += N_NODES * 4;
    int*   loc    = (int*)ws;                         ws += N_NODES * 4;
    int*   bsum   = (int*)ws;                         ws += 512 * 4;
    int*   bsumx  = (int*)ws;                         ws += 512 * 4;
    int*   off    = (int*)ws;                         ws += (N_NODES + 1) * 4;
    int*   cursor = (int*)ws;                         ws += N_NODES * 4;
    int*   ssrc   = (int*)ws;                         ws += (size_t)N_EDGES * 4;

    k_zero   <<<NB_SCAN,        256, 0, stream>>>(cnt);
    k1_proj  <<<N_NODES / 32,   256, 0, stream>>>(feats, W, attn_l, attn_r, z, el, er);
    k_hist   <<<N_EDGES / 256,  256, 0, stream>>>(dst, cnt);
    k_scan1  <<<NB_SCAN,        256, 0, stream>>>(cnt, loc, bsum);
    k_scan2  <<<1,              512, 0, stream>>>(bsum, bsumx);
    k_scan3  <<<NB_SCAN,        256, 0, stream>>>(loc, bsumx, off, cursor);
    k_scatter<<<N_EDGES / 256,  256, 0, stream>>>(src, dst, cursor, ssrc);
    k3_fused <<<N_NODES / 4,    256, 0, stream>>>(ssrc, off, el, er, z, bias, out);
}

// Round 3
// 372.949 us; speedup vs baseline: 1.8065x; 1.3085x over previous
//
#include <hip/hip_runtime.h>

#define N_NODES 100000
#define N_EDGES 1600000
#define IN_F    128
#define HEADS   4
#define OUT_F   16
#define HF      64
#define NEG_SLOPE 0.2f
#define NB_SCAN 391        // ceil(N_NODES/256)
#define NB_MFMA 1563       // ceil(N_NODES/64)

typedef __attribute__((ext_vector_type(8))) short short8;
typedef __attribute__((ext_vector_type(4))) float f32x4;

__device__ __forceinline__ short f2bf(float f) {
    union { float f; unsigned u; } v; v.f = f;
    return (short)((v.u + 0x7FFFu + ((v.u >> 16) & 1u)) >> 16);
}

// ---------------- zero the histogram ----------------
__global__ __launch_bounds__(256) void k_zero(int* __restrict__ cnt) {
    int i = blockIdx.x * 256 + threadIdx.x;
    if (i < N_NODES) cnt[i] = 0;
}

// ---------------- k1: z = feats @ W^T via bf16 MFMA; el/er logits ----------------
// Block = 256 thr = 4 waves; 64 nodes/block (M=64), N=64 cols, K=128.
// A/B fragments staged in LDS pre-swizzled to MFMA layout (lane-contiguous 16B
// -> ds_read_b128, 2-way bank alias only = free).
// 16x16x32 bf16 layouts [learn_hip-verified]:
//   A: row m=lane&15, k=(lane>>4)*8+j   B: col n=lane&15, k=(lane>>4)*8+j
//   C/D: col=lane&15, row=(lane>>4)*4+reg
__global__ __launch_bounds__(256) void k1_mfma(const float* __restrict__ feats,
                                               const float* __restrict__ W,
                                               const float* __restrict__ attn_l,
                                               const float* __restrict__ attn_r,
                                               unsigned short* __restrict__ zb,
                                               float* __restrict__ el,
                                               float* __restrict__ er) {
    __shared__ short Af[4 * 4 * 64 * 8];   // [rt][kf][lane][8] 16 KiB
    __shared__ short Bf[4 * 4 * 64 * 8];   // [ct][kf][lane][8] 16 KiB
    const int t = threadIdx.x;
    const int grp = t >> 6;                 // wave id; doubles as rt (A) / ct (B)
    const int l = t & 63;
    const int q = l >> 4, n = l & 15;

    // ---- stage A (feats rows, fp32 -> bf16) and B (W rows) ----
    int anode = blockIdx.x * 64 + grp * 16 + n;
    int aclamp = anode < N_NODES ? anode : 0;
    const float* arow = feats + (size_t)aclamp * IN_F + q * 8;
    const float* wrow = W + (size_t)(grp * 16 + n) * IN_F + q * 8;
    #pragma unroll
    for (int kf = 0; kf < 4; ++kf) {
        float4 x = *(const float4*)(arow + kf * 32);
        float4 y = *(const float4*)(arow + kf * 32 + 4);
        short8 sa;
        sa[0] = f2bf(x.x); sa[1] = f2bf(x.y); sa[2] = f2bf(x.z); sa[3] = f2bf(x.w);
        sa[4] = f2bf(y.x); sa[5] = f2bf(y.y); sa[6] = f2bf(y.z); sa[7] = f2bf(y.w);
        *(short8*)&Af[((grp * 4 + kf) * 64 + l) * 8] = sa;

        float4 bx = *(const float4*)(wrow + kf * 32);
        float4 by = *(const float4*)(wrow + kf * 32 + 4);
        short8 sb;
        sb[0] = f2bf(bx.x); sb[1] = f2bf(bx.y); sb[2] = f2bf(bx.z); sb[3] = f2bf(bx.w);
        sb[4] = f2bf(by.x); sb[5] = f2bf(by.y); sb[6] = f2bf(by.z); sb[7] = f2bf(by.w);
        *(short8*)&Bf[((grp * 4 + kf) * 64 + l) * 8] = sb;
    }
    __syncthreads();

    // ---- MFMA: wave grp owns row-tile rt=grp, all 4 col-tiles ----
    f32x4 acc[4];
    #pragma unroll
    for (int ct = 0; ct < 4; ++ct) acc[ct] = (f32x4){0.f, 0.f, 0.f, 0.f};
    #pragma unroll
    for (int kf = 0; kf < 4; ++kf) {
        short8 a = *(const short8*)&Af[((grp * 4 + kf) * 64 + l) * 8];
        #pragma unroll
        for (int ct = 0; ct < 4; ++ct) {
            short8 b = *(const short8*)&Bf[((ct * 4 + kf) * 64 + l) * 8];
            acc[ct] = __builtin_amdgcn_mfma_f32_16x16x32_bf16(a, b, acc[ct], 0, 0, 0);
        }
    }

    // ---- epilogue: z (bf16) + el/er head logits ----
    float al[4], ar[4];
    #pragma unroll
    for (int ct = 0; ct < 4; ++ct) {
        al[ct] = attn_l[ct * 16 + n];
        ar[ct] = attn_r[ct * 16 + n];
    }
    #pragma unroll
    for (int reg = 0; reg < 4; ++reg) {
        int onode = blockIdx.x * 64 + grp * 16 + q * 4 + reg;
        bool ok = onode < N_NODES;
        #pragma unroll
        for (int ct = 0; ct < 4; ++ct) {
            float v = acc[ct][reg];
            if (ok) zb[(size_t)onode * HF + ct * 16 + n] = (unsigned short)f2bf(v);
            float vl = v * al[ct], vr = v * ar[ct];
            #pragma unroll
            for (int m = 1; m <= 8; m <<= 1) {
                vl += __shfl_xor(vl, m);
                vr += __shfl_xor(vr, m);
            }
            if (ok && n == 0) {
                el[onode * HEADS + ct] = vl;
                er[onode * HEADS + ct] = vr;
            }
        }
    }
}

// ---------------- counting sort by dst ----------------
__global__ __launch_bounds__(256) void k_hist(const int* __restrict__ dst,
                                              int* __restrict__ cnt) {
    int e = blockIdx.x * 256 + threadIdx.x;
    atomicAdd(&cnt[dst[e]], 1);
}

__global__ __launch_bounds__(256) void k_scan1(const int* __restrict__ cnt,
                                               int* __restrict__ loc,
                                               int* __restrict__ bsum) {
    __shared__ int s[256];
    int t = threadIdx.x, i = blockIdx.x * 256 + t;
    int v = (i < N_NODES) ? cnt[i] : 0;
    s[t] = v; __syncthreads();
    for (int o = 1; o < 256; o <<= 1) {
        int x = (t >= o) ? s[t - o] : 0;
        __syncthreads();
        s[t] += x;
        __syncthreads();
    }
    if (i < N_NODES) loc[i] = s[t] - v;
    if (t == 255) bsum[blockIdx.x] = s[255];
}

__global__ __launch_bounds__(512) void k_scan2(const int* __restrict__ bsum,
                                               int* __restrict__ bsumx) {
    __shared__ int s[512];
    int t = threadIdx.x;
    int v = (t < NB_SCAN) ? bsum[t] : 0;
    s[t] = v; __syncthreads();
    for (int o = 1; o < 512; o <<= 1) {
        int x = (t >= o) ? s[t - o] : 0;
        __syncthreads();
        s[t] += x;
        __syncthreads();
    }
    bsumx[t] = s[t] - v;
}

__global__ __launch_bounds__(256) void k_scan3(const int* __restrict__ loc,
                                               const int* __restrict__ bsumx,
                                               int* __restrict__ off,
                                               int* __restrict__ cursor) {
    int i = blockIdx.x * 256 + threadIdx.x;
    if (i < N_NODES) {
        int o = loc[i] + bsumx[blockIdx.x];
        off[i] = o;
        cursor[i] = o;
    }
    if (i == 0) off[N_NODES] = N_EDGES;
}

__global__ __launch_bounds__(256) void k_scatter(const int* __restrict__ src,
                                                 const int* __restrict__ dst,
                                                 int* __restrict__ cursor,
                                                 int* __restrict__ ssrc) {
    int e = blockIdx.x * 256 + threadIdx.x;
    int d = dst[e];
    int pos = atomicAdd(&cursor[d], 1);
    ssrc[pos] = src[e];
}

// ---------------- fused softmax + aggregation: one wave per node ----------------
// lane = j*16 + q : j = edge slot (4 edges in flight), q = channel quad (bf16 z).
__global__ __launch_bounds__(256) void k3_fused(const int* __restrict__ ssrc,
                                                const int* __restrict__ off,
                                                const float* __restrict__ el,
                                                const float* __restrict__ er,
                                                const unsigned short* __restrict__ zb,
                                                const float* __restrict__ bias,
                                                float* __restrict__ out) {
    const int node = blockIdx.x * 4 + (threadIdx.x >> 6);
    const int lane = threadIdx.x & 63;
    const int j = lane >> 4;
    const int q = lane & 15;
    const int h = q >> 2;
    const int lo = off[node], hi = off[node + 1];
    const float er_d = er[node * HEADS + h];

    float4 acc = make_float4(0.f, 0.f, 0.f, 0.f);
    float den = 0.f;

    for (int i = lo + j; i < hi; i += 4) {
        int s = ssrc[i];
        float x = el[s * HEADS + h] + er_d;
        x = x > 0.f ? x : NEG_SLOPE * x;
        float ex = __expf(x);
        den += ex;
        uint2 v = *(const uint2*)(zb + (size_t)s * HF + q * 4);
        acc.x += ex * __uint_as_float(v.x << 16);
        acc.y += ex * __uint_as_float(v.x & 0xFFFF0000u);
        acc.z += ex * __uint_as_float(v.y << 16);
        acc.w += ex * __uint_as_float(v.y & 0xFFFF0000u);
    }

    #pragma unroll
    for (int m = 16; m <= 32; m <<= 1) {
        acc.x += __shfl_xor(acc.x, m);
        acc.y += __shfl_xor(acc.y, m);
        acc.z += __shfl_xor(acc.z, m);
        acc.w += __shfl_xor(acc.w, m);
        den   += __shfl_xor(den,   m);
    }

    if (j == 0) {
        float4 b = *(const float4*)(bias + q * 4);
        float4 o;
        if (den > 0.f) {
            float inv = 1.f / den;
            o.x = acc.x * inv + b.x; o.y = acc.y * inv + b.y;
            o.z = acc.z * inv + b.z; o.w = acc.w * inv + b.w;
        } else {
            o = b;
        }
        *(float4*)(out + (size_t)node * HF + q * 4) = o;
    }
}

extern "C" void kernel_launch(void* const* d_in, const int* in_sizes, int n_in,
                              void* d_out, int out_size, void* d_ws, size_t ws_size,
                              hipStream_t stream) {
    const float* feats  = (const float*)d_in[0];
    const float* W      = (const float*)d_in[1];
    const float* attn_l = (const float*)d_in[2];
    const float* attn_r = (const float*)d_in[3];
    const float* bias   = (const float*)d_in[4];
    const int*   src    = (const int*)d_in[5];
    const int*   dst    = (const int*)d_in[6];
    float* out = (float*)d_out;

    char* ws = (char*)d_ws;
    unsigned short* zb = (unsigned short*)ws;         ws += (size_t)N_NODES * HF * 2;
    float* el     = (float*)ws;                       ws += N_NODES * HEADS * 4;
    float* er     = (float*)ws;                       ws += N_NODES * HEADS * 4;
    int*   cnt    = (int*)ws;                         ws += N_NODES * 4;
    int*   loc    = (int*)ws;                         ws += N_NODES * 4;
    int*   bsum   = (int*)ws;                         ws += 512 * 4;
    int*   bsumx  = (int*)ws;                         ws += 512 * 4;
    int*   off    = (int*)ws;                         ws += (N_NODES + 1) * 4;
    int*   cursor = (int*)ws;                         ws += N_NODES * 4;
    int*   ssrc   = (int*)ws;                         ws += (size_t)N_EDGES * 4;

    k_zero   <<<NB_SCAN,        256, 0, stream>>>(cnt);
    k1_mfma  <<<NB_MFMA,        256, 0, stream>>>(feats, W, attn_l, attn_r, zb, el, er);
    k_hist   <<<N_EDGES / 256,  256, 0, stream>>>(dst, cnt);
    k_scan1  <<<NB_SCAN,        256, 0, stream>>>(cnt, loc, bsum);
    k_scan2  <<<1,              512, 0, stream>>>(bsum, bsumx);
    k_scan3  <<<NB_SCAN,        256, 0, stream>>>(loc, bsumx, off, cursor);
    k_scatter<<<N_EDGES / 256,  256, 0, stream>>>(src, dst, cursor, ssrc);
    k3_fused <<<N_NODES / 4,    256, 0, stream>>>(ssrc, off, el, er, zb, bias, out);
}